// Round 8
// baseline (434.094 us; speedup 1.0000x reference)
//
#include <hip/hip_runtime.h>
#include <hip/hip_bf16.h>
#include <stdint.h>

#define NN 50000
#define EE 800000
#define DD 64
#define RR 10
#define BB 4
#define NBK2 3125           // 16-node dst-buckets (bucket = dst>>4), 3125*16 = 50000
#define BCAP 512            // fixed record capacity per bucket (mean 256, max ~330)
#define CASTB 1563          // cast blocks
#define BINB 49             // bin blocks, 16384 edges each
#define PREPB 11            // W-prep blocks (10 relations + self-loop)

using u16 = unsigned short;
using u32 = unsigned int;

typedef short v8s __attribute__((ext_vector_type(8)));   // 8 bf16 (4 VGPRs)
typedef float v4f __attribute__((ext_vector_type(4)));   // MFMA accumulator

__device__ __forceinline__ u32 f2bf_rn(float x) {
    u32 u = __float_as_uint(x);
    return (u + 0x7FFFu + ((u >> 16) & 1u)) >> 16;
}
__device__ __forceinline__ u32 pack2bf(float a, float b) {
    return f2bf_rn(a) | (f2bf_rn(b) << 16);
}
__device__ __forceinline__ float bf2f(u16 v) {
    return __uint_as_float(((u32)v) << 16);
}

// ============ k_pre: cast blocks + bin blocks + W-prep blocks ============
// rec word0 = src(16b @0) | etype(4b @16) | dst_local(4b @20); word1 = norm
__global__ __launch_bounds__(256)
void k_pre(const float* __restrict__ feat, const float* __restrict__ weight,
           const float* __restrict__ w_comp, const float* __restrict__ self_w,
           const int* __restrict__ src, const int* __restrict__ dst,
           const int* __restrict__ etype, const float* __restrict__ norm,
           u16* __restrict__ featb, u16* __restrict__ WbT,
           int* __restrict__ bcur, int* __restrict__ flag,
           uint2* __restrict__ rec) {
    const int t = threadIdx.x;
    int bid = blockIdx.x;

    if (bid < CASTB) {
        // ---- feat fp32 -> bf16, one uint4 (8 elems) per thread ----
        int i = bid * 256 + t;
        if (i < NN * DD / 8) {
            float4 f0 = reinterpret_cast<const float4*>(feat)[2 * i];
            float4 f1 = reinterpret_cast<const float4*>(feat)[2 * i + 1];
            uint4 o;
            o.x = pack2bf(f0.x, f0.y);
            o.y = pack2bf(f0.z, f0.w);
            o.z = pack2bf(f1.x, f1.y);
            o.w = pack2bf(f1.z, f1.w);
            reinterpret_cast<uint4*>(featb)[i] = o;
        }
        return;
    }
    bid -= CASTB;

    if (bid < BINB) {
        // ---- bucket binning with batched reservations (R6-proven pattern) ----
        __shared__ int lh[NBK2];
        __shared__ int gb[NBK2];
        __shared__ int lcc[NBK2];
        const int ebase = bid * 16384;
        for (int b = t; b < NBK2; b += 256) { lh[b] = 0; lcc[b] = 0; }
        __syncthreads();
        #pragma unroll 4
        for (int j = 0; j < 64; ++j) {
            int e = ebase + t + 256 * j;
            if (e < EE) atomicAdd(&lh[dst[e] >> 4], 1);
        }
        __syncthreads();
        for (int b = t; b < NBK2; b += 256) {
            int c = lh[b];
            gb[b] = c ? atomicAdd(&bcur[b], c) : 0;
        }
        __syncthreads();
        #pragma unroll 4
        for (int j = 0; j < 64; ++j) {
            int e = ebase + t + 256 * j;
            if (e < EE) {
                int d = dst[e];
                int b = d >> 4;
                int p = gb[b] + atomicAdd(&lcc[b], 1);
                if (p < BCAP) {
                    u32 w0 = (u32)src[e] | ((u32)etype[e] << 16) |
                             ((u32)(d & 15) << 20);
                    rec[b * BCAP + p] = make_uint2(w0, __float_as_uint(norm[e]));
                } else {
                    atomicOr(&flag[b], 1);   // overflow -> k_main edge-rescan
                }
            }
        }
        return;
    }
    bid -= BINB;

    // ---- W-prep: WbT[r][n][k] = W_r[k][n] bf16; r=10 is self-loop ----
    {
        const int r = bid;
        #pragma unroll
        for (int j = 0; j < 16; ++j) {
            int idx = t + 256 * j;           // idx = n*64 + k
            int n = idx >> 6, k = idx & 63;
            float v;
            if (r < RR) {
                v = w_comp[r * BB + 0] * weight[k * 64 + n] +
                    w_comp[r * BB + 1] * weight[4096 + k * 64 + n] +
                    w_comp[r * BB + 2] * weight[8192 + k * 64 + n] +
                    w_comp[r * BB + 3] * weight[12288 + k * 64 + n];
            } else {
                v = self_w[k * 64 + n];
            }
            WbT[(r << 12) + idx] = (u16)f2bf_rn(v);
        }
    }
}

// ============ k_main: one block per 16-node bucket ============
// Phase A: gather-accumulate h[r][node][col] (fp32 LDS, all relations at once).
// Phase B: out-tile = relu( sum_r h[r] @ W_r + featb_tile @ selfW ) via MFMA.
__global__ __launch_bounds__(256, 3)
void k_main(const u16* __restrict__ featb, const u16* __restrict__ WbT,
            const int* __restrict__ bcur, const int* __restrict__ flag,
            const uint2* __restrict__ rec,
            const int* __restrict__ src, const int* __restrict__ dst,
            const int* __restrict__ etype, const float* __restrict__ norm,
            float* __restrict__ out) {
    __shared__ float h[RR * 16 * 68];      // 43520 B; stride 68 spreads banks
    const int t = threadIdx.x;
    const int b = blockIdx.x;
    const int wv = t >> 6;
    const int L = t & 63;
    const int q = L >> 4;
    const int c = L & 15;

    for (int i = t; i < RR * 16 * 68; i += 256) h[i] = 0.f;
    __syncthreads();

    if (__builtin_expect(flag[b] != 0, 0)) {
        // bucket overflow (adversarial input only): rescan raw edge list
        for (int e = t; e < EE; e += 256) {
            int d = dst[e];
            if ((d >> 4) == b) {
                int nl = d & 15;
                const u16* fr = featb + (size_t)src[e] * 64;
                float nm = norm[e];
                float* hr = &h[(etype[e] * 16 + nl) * 68];
                for (int l = 0; l < 64; ++l)
                    atomicAdd(&hr[l], bf2f(fr[l]) * nm);
            }
        }
    } else {
        // each wave owns a contiguous even-aligned chunk; 8 records in flight
        const uint2* rc = rec + (size_t)b * BCAP;
        const int cnt = bcur[b];
        const int chunk = ((cnt + 7) >> 3) << 1;   // even, >= cnt/4
        int lo = wv * chunk;
        int hi = min(lo + chunk, cnt);
        int i = lo;
        #define PROC1(w0, w1) { \
            float fv = bf2f(featb[(size_t)((w0) & 0xFFFFu) * 64 + L]); \
            atomicAdd(&h[((((w0) >> 16) & 0xFu) * 16 + (((w0) >> 20) & 0xFu)) * 68 + L], \
                      fv * __uint_as_float(w1)); }
        for (; i + 8 <= hi; i += 8) {
            uint4 ra = *reinterpret_cast<const uint4*>(&rc[i]);
            uint4 rb = *reinterpret_cast<const uint4*>(&rc[i + 2]);
            uint4 rcx = *reinterpret_cast<const uint4*>(&rc[i + 4]);
            uint4 rd = *reinterpret_cast<const uint4*>(&rc[i + 6]);
            PROC1(ra.x, ra.y)  PROC1(ra.z, ra.w)
            PROC1(rb.x, rb.y)  PROC1(rb.z, rb.w)
            PROC1(rcx.x, rcx.y) PROC1(rcx.z, rcx.w)
            PROC1(rd.x, rd.y)  PROC1(rd.z, rd.w)
        }
        for (; i < hi; ++i) {
            uint2 r0 = rc[i];
            PROC1(r0.x, r0.y)
        }
        #undef PROC1
    }
    __syncthreads();

    // ---- MFMA: D[m=node][n=outcol]; wave wv owns out-cols wv*16..+16 ----
    v4f acc = (v4f)(0.f);
    const int nbase = b * 16;
    #pragma unroll
    for (int r = 0; r <= RR; ++r) {
        v8s af[2], bf[2];
        #pragma unroll
        for (int kh = 0; kh < 2; ++kh) {
            if (r < RR) {
                // A[m=c][k=kh*32+q*8+j] from fp32 h, cvt to bf16 in regs
                const float* hp = &h[(r * 16 + c) * 68 + kh * 32 + q * 8];
                float4 x0 = *reinterpret_cast<const float4*>(hp);
                float4 x1 = *reinterpret_cast<const float4*>(hp + 4);
                union { uint4 u; v8s v; } cv;
                cv.u = make_uint4(pack2bf(x0.x, x0.y), pack2bf(x0.z, x0.w),
                                  pack2bf(x1.x, x1.y), pack2bf(x1.z, x1.w));
                af[kh] = cv.v;
            } else {
                // self-loop: A directly from featb (bf16 global, L2-hot)
                af[kh] = *reinterpret_cast<const v8s*>(
                    featb + (size_t)(nbase + c) * 64 + kh * 32 + q * 8);
            }
            // B[n=wv*16+c][k] from precomputed WbT (L2-hot)
            bf[kh] = *reinterpret_cast<const v8s*>(
                WbT + ((r * 64 + wv * 16 + c) << 6) + kh * 32 + q * 8);
        }
        acc = __builtin_amdgcn_mfma_f32_16x16x32_bf16(af[0], bf[0], acc, 0, 0, 0);
        acc = __builtin_amdgcn_mfma_f32_16x16x32_bf16(af[1], bf[1], acc, 0, 0, 0);
    }

    // epilogue: D[m=q*4+rg][n=c]; fused ReLU; out written exactly once
    #pragma unroll
    for (int rg = 0; rg < 4; ++rg)
        out[(size_t)(nbase + q * 4 + rg) * 64 + wv * 16 + c] = fmaxf(acc[rg], 0.f);
}

// ---------------- fallbacks (only if workspace is tiny) ----------------
__global__ __launch_bounds__(256)
void k_self(const float* __restrict__ feat, const float* __restrict__ self_w,
            float* __restrict__ out) {
    int n = (blockIdx.x * 256 + threadIdx.x) >> 6;
    int o = threadIdx.x & 63;
    if (n >= NN) return;
    float acc = 0.f;
    for (int i = 0; i < 64; ++i)
        acc = fmaf(feat[(size_t)n * 64 + i], self_w[i * 64 + o], acc);
    out[(size_t)n * 64 + o] = acc;
}

__global__ void k_makeW(const float* __restrict__ weight,
                        const float* __restrict__ w_comp,
                        float* __restrict__ W) {
    int f = blockIdx.x * 256 + threadIdx.x;
    if (f >= RR * 4096) return;
    int r = f >> 12;
    int io = f & 4095;
    float v = 0.f;
    #pragma unroll
    for (int b = 0; b < BB; ++b) v += w_comp[r * BB + b] * weight[b * 4096 + io];
    W[f] = v;
}

__global__ __launch_bounds__(256)
void k_edges_direct(const int* __restrict__ src, const int* __restrict__ dst,
                    const int* __restrict__ etype, const float* __restrict__ norm,
                    const float* __restrict__ feat, const float* __restrict__ W,
                    float* __restrict__ out) {
    int gtid = blockIdx.x * 256 + threadIdx.x;
    int e = gtid >> 6;
    int lane = gtid & 63;
    if (e >= EE) return;
    int s = src[e];
    int d = dst[e];
    int rt = etype[e];
    float nm = norm[e];
    const float* fr = feat + (size_t)s * DD;
    const float* Wr = W + (size_t)rt * 4096;
    float acc = 0.f;
    #pragma unroll
    for (int i = 0; i < DD; ++i) acc = fmaf(fr[i], Wr[i * DD + lane], acc);
    atomicAdd(&out[(size_t)d * DD + lane], acc * nm);
}

__global__ __launch_bounds__(256)
void k_edges_nows(const int* __restrict__ src, const int* __restrict__ dst,
                  const int* __restrict__ etype, const float* __restrict__ norm,
                  const float* __restrict__ feat, const float* __restrict__ weight,
                  const float* __restrict__ w_comp, float* __restrict__ out) {
    int gtid = blockIdx.x * 256 + threadIdx.x;
    int e = gtid >> 6;
    int lane = gtid & 63;
    if (e >= EE) return;
    int s = src[e];
    int d = dst[e];
    int rt = etype[e];
    float nm = norm[e];
    float c0 = w_comp[rt * 4 + 0], c1 = w_comp[rt * 4 + 1];
    float c2 = w_comp[rt * 4 + 2], c3 = w_comp[rt * 4 + 3];
    float acc = 0.f;
    for (int i = 0; i < 64; ++i) {
        float w = c0 * weight[i * 64 + lane] + c1 * weight[4096 + i * 64 + lane] +
                  c2 * weight[8192 + i * 64 + lane] + c3 * weight[12288 + i * 64 + lane];
        acc = fmaf(feat[(size_t)s * 64 + i], w, acc);
    }
    atomicAdd(&out[(size_t)d * 64 + lane], acc * nm);
}

__global__ __launch_bounds__(256)
void k_relu(float* __restrict__ out) {
    int i = blockIdx.x * 256 + threadIdx.x;
    float4* p = reinterpret_cast<float4*>(out);
    float4 v = p[i];
    v.x = fmaxf(v.x, 0.f);
    v.y = fmaxf(v.y, 0.f);
    v.z = fmaxf(v.z, 0.f);
    v.w = fmaxf(v.w, 0.f);
    p[i] = v;
}

extern "C" void kernel_launch(void* const* d_in, const int* in_sizes, int n_in,
                              void* d_out, int out_size, void* d_ws, size_t ws_size,
                              hipStream_t stream) {
    const float* feat   = (const float*)d_in[0];
    const int*   src    = (const int*)d_in[1];
    const int*   dst    = (const int*)d_in[2];
    const int*   etype  = (const int*)d_in[3];
    const float* norm   = (const float*)d_in[4];
    const float* weight = (const float*)d_in[5];
    const float* w_comp = (const float*)d_in[6];
    const float* self_w = (const float*)d_in[7];
    float* out = (float*)d_out;

    // ws layout
    const size_t off_featb = 0;                          // 6,400,000 B
    const size_t off_W     = 6400000;                    // 11*4096*2 = 90,112
    const size_t off_bcur  = off_W + 90112;              // 3125 ints
    const size_t off_flag  = off_bcur + 12500;           // 3125 ints
    const size_t off_rec   = off_flag + 12500 + 8;       // 16B-aligned: 6,515,120
    const size_t need_main = off_rec + (size_t)NBK2 * BCAP * 8;  // ~19.3 MB

    dim3 blk(256);
    char* ws = (char*)d_ws;

    if (ws_size >= need_main) {
        u16*  featb = (u16*)(ws + off_featb);
        u16*  WbT   = (u16*)(ws + off_W);
        int*  bcur  = (int*)(ws + off_bcur);
        int*  flag  = (int*)(ws + off_flag);
        uint2* rec  = (uint2*)(ws + off_rec);

        hipMemsetAsync(bcur, 0, 25000, stream);          // bcur + flag
        k_pre<<<dim3(CASTB + BINB + PREPB), blk, 0, stream>>>(
            feat, weight, w_comp, self_w, src, dst, etype, norm,
            featb, WbT, bcur, flag, rec);
        k_main<<<dim3(NBK2), blk, 0, stream>>>(
            featb, WbT, bcur, flag, rec, src, dst, etype, norm, out);
    } else if (ws_size >= (size_t)RR * 4096 * 4) {
        float* W = (float*)d_ws;
        k_self<<<dim3(NN * 64 / 256), blk, 0, stream>>>(feat, self_w, out);
        k_makeW<<<dim3(160), blk, 0, stream>>>(weight, w_comp, W);
        k_edges_direct<<<dim3(EE * 64 / 256), blk, 0, stream>>>(src, dst, etype, norm,
                                                                feat, W, out);
        k_relu<<<dim3(NN * DD / 4 / 256), blk, 0, stream>>>(out);
    } else {
        k_self<<<dim3(NN * 64 / 256), blk, 0, stream>>>(feat, self_w, out);
        k_edges_nows<<<dim3(EE * 64 / 256), blk, 0, stream>>>(src, dst, etype, norm,
                                                              feat, weight, w_comp, out);
        k_relu<<<dim3(NN * DD / 4 / 256), blk, 0, stream>>>(out);
    }
}

// Round 9
// 167.341 us; speedup vs baseline: 2.5941x; 2.5941x over previous
//
#include <hip/hip_runtime.h>
#include <hip/hip_bf16.h>
#include <stdint.h>

#define NN 50000
#define EE 800000
#define DD 64
#define RR 10
#define BB 4
#define NPAD 50176
#define NBKT 391            // buckets of 128 nodes
#define TBLK 4301           // 391 * 11 transform blocks in k_big
#define BBLK 196            // bin blocks in k_big (4096 edges each)
#define PADCAP 8192         // sortb2 LDS buffer entries (padded layout)
#define FCAP 4096           // fixed-capacity bucket stride (records per bucket)

using u16 = unsigned short;
using u32 = unsigned int;

typedef short v8s __attribute__((ext_vector_type(8)));
typedef float v4f __attribute__((ext_vector_type(4)));

__device__ __forceinline__ u32 f2bf_rn(float x) {
    u32 u = __float_as_uint(x);
    return (u + 0x7FFFu + ((u >> 16) & 1u)) >> 16;
}
__device__ __forceinline__ u32 pack2bf(float a, float b) {
    return f2bf_rn(a) | (f2bf_rn(b) << 16);
}

// ============ mega-kernel: bin blocks (first) + transform blocks ============
// rec word0 = src(16b) | etype(4b @16) | dst_local(7b @20)
// cap==0: hist mode (bcur preset to exact bucket bases). cap>0: fixed mode
// (bcur zeroed; rec slot = b*cap + local; overflow -> flag|=2).
__global__ __launch_bounds__(256, 2)
void k_big(const float* __restrict__ feat,
           const float* __restrict__ weight,
           const float* __restrict__ w_comp,
           const float* __restrict__ self_w,
           const int* __restrict__ src, const int* __restrict__ dst,
           const int* __restrict__ etype, const float* __restrict__ norm,
           int* __restrict__ bcur, int* __restrict__ flag,
           uint2* __restrict__ rec,
           u16* __restrict__ xr, float* __restrict__ out,
           int nbin, int tb_off, int cap) {
    __shared__ __align__(16) char smem[34816];
    const int t = threadIdx.x;

    if ((int)blockIdx.x < nbin) {
        // ---------------- bucket binning, batched reservations --------------
        int* lh  = (int*)smem;
        int* gb  = lh + 392;
        int* lcc = gb + 392;
        const int ebase = (int)blockIdx.x * 4096;
        for (int b = t; b < 392; b += 256) { lh[b] = 0; lcc[b] = 0; }
        __syncthreads();
        #pragma unroll 4
        for (int j = 0; j < 16; ++j) {
            int e = ebase + t + 256 * j;
            if (e < EE) atomicAdd(&lh[dst[e] >> 7], 1);
        }
        __syncthreads();
        for (int b = t; b < 392; b += 256) {
            int c = lh[b];
            gb[b] = c ? atomicAdd(&bcur[b], c) : 0;
        }
        __syncthreads();
        #pragma unroll 4
        for (int j = 0; j < 16; ++j) {
            int e = ebase + t + 256 * j;
            if (e < EE) {
                int d = dst[e];
                int b = d >> 7;
                int p = atomicAdd(&lcc[b], 1);
                u32 w0 = (u32)src[e] | ((u32)etype[e] << 16) | ((u32)(d & 127) << 20);
                if (cap) {
                    int il = gb[b] + p;
                    if (il < cap)
                        rec[(size_t)b * cap + il] = make_uint2(w0, __float_as_uint(norm[e]));
                    else
                        atomicOr(&flag[b], 2);
                } else {
                    rec[gb[b] + p] = make_uint2(w0, __float_as_uint(norm[e]));
                }
            }
        }
        return;
    }

    // ---------------- transform ----------------
    u16*   sWt = (u16*)smem;                  // Wt[n][k], stride 72 u16
    u16*   sFb = (u16*)(smem + 9216);         // feat bf16 [128][72]
    float* sD  = (float*)smem;                // epilogue transpose [128][68]

    const int tb = (int)blockIdx.x - nbin + tb_off;
    const int r = tb / 391;
    const int nbase = (tb % 391) * 128;

    if (r < RR) {
        const float c0 = w_comp[r * BB + 0];
        const float c1 = w_comp[r * BB + 1];
        const float c2 = w_comp[r * BB + 2];
        const float c3 = w_comp[r * BB + 3];
        #pragma unroll
        for (int qq = 0; qq < 16; ++qq) {
            int idx = t + 256 * qq;
            int n = idx & 63, k = idx >> 6;
            float v = c0 * weight[k * 64 + n] + c1 * weight[4096 + k * 64 + n] +
                      c2 * weight[8192 + k * 64 + n] + c3 * weight[12288 + k * 64 + n];
            sWt[n * 72 + k] = (u16)f2bf_rn(v);
        }
    } else {
        #pragma unroll
        for (int qq = 0; qq < 16; ++qq) {
            int idx = t + 256 * qq;
            int n = idx & 63, k = idx >> 6;
            sWt[n * 72 + k] = (u16)f2bf_rn(self_w[k * 64 + n]);
        }
    }

    #pragma unroll
    for (int qq = 0; qq < 8; ++qq) {
        int f4 = qq * 256 + t;
        int nl = f4 >> 4;
        int ic = (f4 & 15) << 2;
        int n = nbase + nl;
        float4 v = make_float4(0.f, 0.f, 0.f, 0.f);
        if (n < NN) v = reinterpret_cast<const float4*>(feat)[(size_t)n * 16 + (f4 & 15)];
        *reinterpret_cast<uint2*>(&sFb[nl * 72 + ic]) =
            make_uint2(pack2bf(v.x, v.y), pack2bf(v.z, v.w));
    }
    __syncthreads();

    const int wv = t >> 6;
    const int L = t & 63;
    const int q = L >> 4;
    const int c = L & 15;

    v8s bf[4][2];
    #pragma unroll
    for (int nt = 0; nt < 4; ++nt)
        #pragma unroll
        for (int kh = 0; kh < 2; ++kh)
            bf[nt][kh] = *reinterpret_cast<const v8s*>(&sWt[(nt * 16 + c) * 72 + kh * 32 + q * 8]);

    v8s af[2][2];
    #pragma unroll
    for (int mt = 0; mt < 2; ++mt) {
        int row = wv * 32 + mt * 16 + c;
        #pragma unroll
        for (int kh = 0; kh < 2; ++kh)
            af[mt][kh] = *reinterpret_cast<const v8s*>(&sFb[row * 72 + kh * 32 + q * 8]);
    }
    __syncthreads();

    v4f acc[2][4];
    #pragma unroll
    for (int mt = 0; mt < 2; ++mt)
        #pragma unroll
        for (int nt = 0; nt < 4; ++nt) {
            acc[mt][nt] = (v4f)(0.f);
            #pragma unroll
            for (int kh = 0; kh < 2; ++kh)
                acc[mt][nt] = __builtin_amdgcn_mfma_f32_16x16x32_bf16(
                    af[mt][kh], bf[nt][kh], acc[mt][nt], 0, 0, 0);
        }

    #pragma unroll
    for (int mt = 0; mt < 2; ++mt) {
        int mrow = wv * 32 + mt * 16 + q * 4;
        #pragma unroll
        for (int nt = 0; nt < 4; ++nt)
            #pragma unroll
            for (int rg = 0; rg < 4; ++rg)
                sD[(mrow + rg) * 68 + nt * 16 + c] = acc[mt][nt][rg];
    }
    __syncthreads();

    const int row = t >> 1;
    const int cb = (t & 1) * 32;
    const int g = nbase + row;
    if (g < NN) {
        const float* sp = &sD[row * 68 + cb];
        if (r < RR) {
            u16* dp = xr + ((size_t)r * NN + g) * DD + cb;
            #pragma unroll
            for (int j = 0; j < 4; ++j) {
                float4 f0 = *reinterpret_cast<const float4*>(sp + j * 8);
                float4 f1 = *reinterpret_cast<const float4*>(sp + j * 8 + 4);
                uint4 o;
                o.x = pack2bf(f0.x, f0.y);
                o.y = pack2bf(f0.z, f0.w);
                o.z = pack2bf(f1.x, f1.y);
                o.w = pack2bf(f1.z, f1.w);
                *reinterpret_cast<uint4*>(dp + j * 8) = o;
            }
        } else {
            float* dp = out + (size_t)g * DD + cb;
            #pragma unroll
            for (int j = 0; j < 8; ++j)
                *reinterpret_cast<float4*>(dp + j * 4) =
                    *reinterpret_cast<const float4*>(sp + j * 4);
        }
    }
}

// ---------------- bucket histogram (hist mode) ----------------
__global__ __launch_bounds__(256)
void k_bhist(const int* __restrict__ dst, int* __restrict__ bktcnt) {
    __shared__ int lh[NBKT];
    const int t = threadIdx.x;
    for (int b = t; b < NBKT; b += 256) lh[b] = 0;
    __syncthreads();
    const int ebase = blockIdx.x * 8192;
    #pragma unroll
    for (int j = 0; j < 32; ++j) {
        int e = ebase + t + 256 * j;
        if (e < EE) atomicAdd(&lh[dst[e] >> 7], 1);
    }
    __syncthreads();
    for (int b = t; b < NBKT; b += 256) {
        int v = lh[b];
        if (v) atomicAdd(&bktcnt[b], v);
    }
}

// ---------------- bucket scan (hist mode) ----------------
__global__ __launch_bounds__(512)
void k_bscan(const int* __restrict__ bktcnt, int* __restrict__ bktbase,
             int* __restrict__ bcur, int* __restrict__ flag) {
    __shared__ int s[512];
    int t = threadIdx.x;
    int v = (t < NBKT) ? bktcnt[t] : 0;
    s[t] = v;
    __syncthreads();
    #pragma unroll
    for (int off = 1; off < 512; off <<= 1) {
        int x = (t >= off) ? s[t - off] : 0;
        __syncthreads();
        s[t] += x;
        __syncthreads();
    }
    if (t < 392) {
        int b = s[t] - v;
        bktbase[t] = b;
        bcur[t] = b;
        flag[t] = 0;
    }
}

// ------ sort bucket segment in place + per-node base/cnt (padded to 16) ------
__global__ __launch_bounds__(512)
void k_sortb2(const int* __restrict__ bcurF, const int* __restrict__ bktbase,
              int* __restrict__ flag, uint2* __restrict__ rec,
              int* __restrict__ base, int* __restrict__ cnt, int cap) {
    __shared__ uint2 buf[PADCAP];     // 64 KB
    __shared__ int h[128];
    __shared__ int pc[128];
    __shared__ int sc[128];
    __shared__ int lc[128];
    __shared__ int totp;
    const int b = blockIdx.x;
    const int t = threadIdx.x;
    const int seg0 = cap ? b * cap : bktbase[b];
    const int cnt_b = cap ? bcurF[b] : (bcurF[b] - seg0);
    if (flag[b] & 2) return;                 // binning overflow
    if (cnt_b > 6144) {
        if (t == 0) flag[b] = 1;             // rec-scan fallback in k_agg
        return;
    }
    if (t < 128) h[t] = 0;
    __syncthreads();
    // histogram of dst_local (records also staged... read pass 1: hist only)
    for (int k = t; k < cnt_b; k += 512)
        atomicAdd(&h[(rec[seg0 + k].x >> 20) & 127], 1);
    __syncthreads();
    // padded counts (fixed mode pads to x16; hist mode exact) + exclusive scan
    if (t < 128) {
        pc[t] = cap ? ((h[t] + 15) & ~15) : h[t];
        sc[t] = pc[t];
    }
    __syncthreads();
    #pragma unroll
    for (int off = 1; off < 128; off <<= 1) {
        int x = 0;
        if (t < 128 && t >= off) x = sc[t - off];
        __syncthreads();
        if (t < 128) sc[t] += x;
        __syncthreads();
    }
    if (t == 127) totp = sc[127];
    __syncthreads();
    const int total = totp;
    if (total > PADCAP || (cap && total > cap)) {
        if (t == 0) flag[b] = 1;
        return;
    }
    if (t < 128) {
        int ex = sc[t] - pc[t];
        lc[t] = ex;
        base[b * 128 + t] = seg0 + ex;
        cnt[b * 128 + t] = pc[t];
    }
    // zero buf (pads become zero-records = exact no-ops in k_agg)
    for (int k = t; k < total; k += 512) buf[k] = make_uint2(0u, 0u);
    __syncthreads();
    // scatter into padded sorted order, then coalesced writeback
    for (int k = t; k < cnt_b; k += 512) {
        uint2 rr = rec[seg0 + k];
        int p = atomicAdd(&lc[(rr.x >> 20) & 127], 1);
        buf[p] = rr;
    }
    __syncthreads();
    for (int k = t; k < total; k += 512)
        rec[seg0 + k] = buf[k];
}

// ------ aggregate: one wave per dst node, 16 records in flight -------
__global__ __launch_bounds__(256)
void k_agg(const int* __restrict__ base, const int* __restrict__ cnt,
           const uint2* __restrict__ rec, const u16* __restrict__ xr,
           const int* __restrict__ flag, const int* __restrict__ bktbase,
           const int* __restrict__ bcurF,
           const int* __restrict__ src, const int* __restrict__ dst,
           const int* __restrict__ etype, const float* __restrict__ norm,
           int cap, float* __restrict__ out) {
    int n = (blockIdx.x * 256 + threadIdx.x) >> 6;
    int L = threadIdx.x & 63;
    if (n >= NN) return;
    const int g = L >> 4;        // record group 0..3
    const int c = L & 15;        // cols 4c..4c+3
    float a0 = 0.f, a1 = 0.f, a2 = 0.f, a3 = 0.f;
    const int fb = flag[n >> 7];

    if (__builtin_expect(fb == 0, 1)) {
        int st = base[n];
        int cn = cnt[n];
        int k = 0;
        for (; k + 16 <= cn; k += 16) {
            uint2 r0 = rec[st + k + g];
            uint2 r1 = rec[st + k + 4 + g];
            uint2 r2 = rec[st + k + 8 + g];
            uint2 r3 = rec[st + k + 12 + g];
            size_t w0 = ((size_t)((r0.x >> 16) & 0xFu) * NN + (r0.x & 0xFFFFu)) * DD;
            size_t w1 = ((size_t)((r1.x >> 16) & 0xFu) * NN + (r1.x & 0xFFFFu)) * DD;
            size_t w2 = ((size_t)((r2.x >> 16) & 0xFu) * NN + (r2.x & 0xFFFFu)) * DD;
            size_t w3 = ((size_t)((r3.x >> 16) & 0xFu) * NN + (r3.x & 0xFFFFu)) * DD;
            uint2 u0 = *reinterpret_cast<const uint2*>(&xr[w0 + 4 * c]);
            uint2 u1 = *reinterpret_cast<const uint2*>(&xr[w1 + 4 * c]);
            uint2 u2 = *reinterpret_cast<const uint2*>(&xr[w2 + 4 * c]);
            uint2 u3 = *reinterpret_cast<const uint2*>(&xr[w3 + 4 * c]);
            float n0 = __uint_as_float(r0.y), n1 = __uint_as_float(r1.y);
            float n2 = __uint_as_float(r2.y), n3 = __uint_as_float(r3.y);
            a0 = fmaf(__uint_as_float((u0.x & 0xFFFFu) << 16), n0, a0);
            a1 = fmaf(__uint_as_float(u0.x & 0xFFFF0000u), n0, a1);
            a2 = fmaf(__uint_as_float((u0.y & 0xFFFFu) << 16), n0, a2);
            a3 = fmaf(__uint_as_float(u0.y & 0xFFFF0000u), n0, a3);
            a0 = fmaf(__uint_as_float((u1.x & 0xFFFFu) << 16), n1, a0);
            a1 = fmaf(__uint_as_float(u1.x & 0xFFFF0000u), n1, a1);
            a2 = fmaf(__uint_as_float((u1.y & 0xFFFFu) << 16), n1, a2);
            a3 = fmaf(__uint_as_float(u1.y & 0xFFFF0000u), n1, a3);
            a0 = fmaf(__uint_as_float((u2.x & 0xFFFFu) << 16), n2, a0);
            a1 = fmaf(__uint_as_float(u2.x & 0xFFFF0000u), n2, a1);
            a2 = fmaf(__uint_as_float((u2.y & 0xFFFFu) << 16), n2, a2);
            a3 = fmaf(__uint_as_float(u2.y & 0xFFFF0000u), n2, a3);
            a0 = fmaf(__uint_as_float((u3.x & 0xFFFFu) << 16), n3, a0);
            a1 = fmaf(__uint_as_float(u3.x & 0xFFFF0000u), n3, a1);
            a2 = fmaf(__uint_as_float((u3.y & 0xFFFFu) << 16), n3, a2);
            a3 = fmaf(__uint_as_float(u3.y & 0xFFFF0000u), n3, a3);
        }
        for (int kk = k + g; kk < cn; kk += 4) {
            uint2 rr = rec[st + kk];
            size_t rw = ((size_t)((rr.x >> 16) & 0xFu) * NN + (rr.x & 0xFFFFu)) * DD;
            uint2 u = *reinterpret_cast<const uint2*>(&xr[rw + 4 * c]);
            float nm = __uint_as_float(rr.y);
            a0 = fmaf(__uint_as_float((u.x & 0xFFFFu) << 16), nm, a0);
            a1 = fmaf(__uint_as_float(u.x & 0xFFFF0000u), nm, a1);
            a2 = fmaf(__uint_as_float((u.y & 0xFFFFu) << 16), nm, a2);
            a3 = fmaf(__uint_as_float(u.y & 0xFFFF0000u), nm, a3);
        }
    } else if (fb & 2) {
        for (int e = g; e < EE; e += 4) {
            if (dst[e] == n) {
                size_t rw = ((size_t)etype[e] * NN + src[e]) * DD;
                uint2 u = *reinterpret_cast<const uint2*>(&xr[rw + 4 * c]);
                float nm = norm[e];
                a0 = fmaf(__uint_as_float((u.x & 0xFFFFu) << 16), nm, a0);
                a1 = fmaf(__uint_as_float(u.x & 0xFFFF0000u), nm, a1);
                a2 = fmaf(__uint_as_float((u.y & 0xFFFFu) << 16), nm, a2);
                a3 = fmaf(__uint_as_float(u.y & 0xFFFF0000u), nm, a3);
            }
        }
    } else {
        int b = n >> 7;
        int seg0 = cap ? b * cap : bktbase[b];
        int segend = cap ? (b * cap + bcurF[b]) : bcurF[b];
        int my = n & 127;
        for (int k = seg0 + g; k < segend; k += 4) {
            uint2 rr = rec[k];
            if (((rr.x >> 20) & 127) == (u32)my) {
                size_t rw = ((size_t)((rr.x >> 16) & 0xFu) * NN + (rr.x & 0xFFFFu)) * DD;
                uint2 u = *reinterpret_cast<const uint2*>(&xr[rw + 4 * c]);
                float nm = __uint_as_float(rr.y);
                a0 = fmaf(__uint_as_float((u.x & 0xFFFFu) << 16), nm, a0);
                a1 = fmaf(__uint_as_float(u.x & 0xFFFF0000u), nm, a1);
                a2 = fmaf(__uint_as_float((u.y & 0xFFFFu) << 16), nm, a2);
                a3 = fmaf(__uint_as_float(u.y & 0xFFFF0000u), nm, a3);
            }
        }
    }
    a0 += __shfl_xor(a0, 16); a1 += __shfl_xor(a1, 16);
    a2 += __shfl_xor(a2, 16); a3 += __shfl_xor(a3, 16);
    a0 += __shfl_xor(a0, 32); a1 += __shfl_xor(a1, 32);
    a2 += __shfl_xor(a2, 32); a3 += __shfl_xor(a3, 32);
    if (g == 0) {
        size_t o = (size_t)n * DD + 4 * c;
        float4 v = *reinterpret_cast<const float4*>(&out[o]);
        v.x = fmaxf(v.x + a0, 0.f);
        v.y = fmaxf(v.y + a1, 0.f);
        v.z = fmaxf(v.z + a2, 0.f);
        v.w = fmaxf(v.w + a3, 0.f);
        *reinterpret_cast<float4*>(&out[o]) = v;
    }
}

// ---------------- fallbacks ----------------
__global__ __launch_bounds__(256)
void k_edges(const int* __restrict__ src, const int* __restrict__ dst,
             const int* __restrict__ etype, const float* __restrict__ norm,
             const u16* __restrict__ xr, float* __restrict__ out) {
    int gtid = blockIdx.x * 256 + threadIdx.x;
    int e = gtid >> 4;
    int l = gtid & 15;
    if (e >= EE) return;
    int s = src[e];
    int d = dst[e];
    int rt = etype[e];
    float nm = norm[e];
    size_t row = ((size_t)rt * NN + s) * DD;
    uint2 u = *reinterpret_cast<const uint2*>(&xr[row + l * 4]);
    float f0 = __uint_as_float((u.x & 0xFFFFu) << 16);
    float f1 = __uint_as_float(u.x & 0xFFFF0000u);
    float f2 = __uint_as_float((u.y & 0xFFFFu) << 16);
    float f3 = __uint_as_float(u.y & 0xFFFF0000u);
    float* op = out + (size_t)d * DD + l * 4;
    atomicAdd(op + 0, f0 * nm);
    atomicAdd(op + 1, f1 * nm);
    atomicAdd(op + 2, f2 * nm);
    atomicAdd(op + 3, f3 * nm);
}

__global__ void k_makeW(const float* __restrict__ weight,
                        const float* __restrict__ w_comp,
                        float* __restrict__ W) {
    int f = blockIdx.x * 256 + threadIdx.x;
    if (f >= RR * 4096) return;
    int r = f >> 12;
    int io = f & 4095;
    float v = 0.f;
    #pragma unroll
    for (int b = 0; b < BB; ++b) v += w_comp[r * BB + b] * weight[b * 4096 + io];
    W[f] = v;
}

__global__ __launch_bounds__(256)
void k_edges_direct(const int* __restrict__ src, const int* __restrict__ dst,
                    const int* __restrict__ etype, const float* __restrict__ norm,
                    const float* __restrict__ feat, const float* __restrict__ W,
                    float* __restrict__ out) {
    int gtid = blockIdx.x * 256 + threadIdx.x;
    int e = gtid >> 6;
    int lane = gtid & 63;
    if (e >= EE) return;
    int s = src[e];
    int d = dst[e];
    int rt = etype[e];
    float nm = norm[e];
    const float* fr = feat + (size_t)s * DD;
    const float* Wr = W + (size_t)rt * 4096;
    float acc = 0.f;
    #pragma unroll
    for (int i = 0; i < DD; ++i) acc = fmaf(fr[i], Wr[i * DD + lane], acc);
    atomicAdd(&out[(size_t)d * DD + lane], acc * nm);
}

__global__ __launch_bounds__(256)
void k_relu(float* __restrict__ out) {
    int i = blockIdx.x * 256 + threadIdx.x;
    float4* p = reinterpret_cast<float4*>(out);
    float4 v = p[i];
    v.x = fmaxf(v.x, 0.f);
    v.y = fmaxf(v.y, 0.f);
    v.z = fmaxf(v.z, 0.f);
    v.w = fmaxf(v.w, 0.f);
    p[i] = v;
}

extern "C" void kernel_launch(void* const* d_in, const int* in_sizes, int n_in,
                              void* d_out, int out_size, void* d_ws, size_t ws_size,
                              hipStream_t stream) {
    const float* feat   = (const float*)d_in[0];
    const int*   src    = (const int*)d_in[1];
    const int*   dst    = (const int*)d_in[2];
    const int*   etype  = (const int*)d_in[3];
    const float* norm   = (const float*)d_in[4];
    const float* weight = (const float*)d_in[5];
    const float* w_comp = (const float*)d_in[6];
    const float* self_w = (const float*)d_in[7];
    float* out = (float*)d_out;

    const size_t sz_xr     = (size_t)RR * NN * DD * sizeof(u16);  // 64,000,000
    const size_t off_bkc   = sz_xr;                 // bktcnt 392 ints -> 1600
    const size_t off_bkb   = off_bkc + 1600;        // bktbase
    const size_t off_bcur  = off_bkb + 1600;        // bcur
    const size_t off_flag  = off_bcur + 1600;       // flag
    const size_t off_base  = off_flag + 1600;       // NPAD ints
    const size_t off_cnt   = off_base + (size_t)NPAD * 4;
    const size_t off_rec   = off_cnt + (size_t)NPAD * 4;
    const size_t need_hist  = off_rec + (size_t)EE * 8;            // ~70.8 MB
    const size_t need_fixed = off_rec + (size_t)NBKT * FCAP * 8;   // ~77.2 MB

    dim3 blk(256);
    char* ws = (char*)d_ws;

    if (ws_size >= need_hist) {
        u16*  xr      = (u16*)ws;
        int*  bktcnt  = (int*)(ws + off_bkc);
        int*  bktbase = (int*)(ws + off_bkb);
        int*  bcur    = (int*)(ws + off_bcur);
        int*  flag    = (int*)(ws + off_flag);
        int*  basep   = (int*)(ws + off_base);
        int*  cntp    = (int*)(ws + off_cnt);
        uint2* rec    = (uint2*)(ws + off_rec);
        const int cap = (ws_size >= need_fixed) ? FCAP : 0;

        // zero bktcnt + bktbase + bcur + flag in one shot
        hipMemsetAsync(bktcnt, 0, 6400, stream);
        if (!cap) {
            k_bhist<<<dim3(98), blk, 0, stream>>>(dst, bktcnt);
            k_bscan<<<dim3(1), dim3(512), 0, stream>>>(bktcnt, bktbase, bcur, flag);
        }
        k_big<<<dim3(TBLK + BBLK), blk, 0, stream>>>(feat, weight, w_comp, self_w,
                                                     src, dst, etype, norm,
                                                     bcur, flag, rec, xr, out,
                                                     BBLK, 0, cap);
        k_sortb2<<<dim3(NBKT), dim3(512), 0, stream>>>(bcur, bktbase, flag, rec,
                                                       basep, cntp, cap);
        k_agg<<<dim3((NN * 64 + 255) / 256), blk, 0, stream>>>(
            basep, cntp, rec, xr, flag, bktbase, bcur,
            src, dst, etype, norm, cap, out);
    } else if (ws_size >= sz_xr) {
        u16* xr = (u16*)d_ws;
        k_big<<<dim3(TBLK), blk, 0, stream>>>(feat, weight, w_comp, self_w,
                                              src, dst, etype, norm,
                                              (int*)d_ws, (int*)d_ws, (uint2*)d_ws,
                                              xr, out, 0, 0, 0);
        k_edges<<<dim3(EE * 16 / 256), blk, 0, stream>>>(src, dst, etype, norm, xr, out);
        k_relu<<<dim3(NN * DD / 4 / 256), blk, 0, stream>>>(out);
    } else {
        k_big<<<dim3(391), blk, 0, stream>>>(feat, weight, w_comp, self_w,
                                             src, dst, etype, norm,
                                             (int*)d_ws, (int*)d_ws, (uint2*)d_ws,
                                             (u16*)d_ws, out, 0, 3910, 0);
        float* W = (float*)d_ws;
        k_makeW<<<dim3(160), blk, 0, stream>>>(weight, w_comp, W);
        k_edges_direct<<<dim3(EE * 64 / 256), blk, 0, stream>>>(src, dst, etype, norm,
                                                                feat, W, out);
        k_relu<<<dim3(NN * DD / 4 / 256), blk, 0, stream>>>(out);
    }
}